// Round 8
// baseline (62605.627 us; speedup 1.0000x reference)
//
#include <hip/hip_runtime.h>
#include <math.h>

#define T_STEPS 200
#define BATCH   64
#define VOCAB   256
#define EMB     512
#define HN      1024
#define ON_     1024
#define SDIM    4096   // 4*HN
#define NBLK    512
#define BHN     (BATCH * HN)   // 65536
#define NGRP    16
#define GSZ     (NBLK / NGRP)  // 32

__device__ __forceinline__ float sigmoidf_(float x) {
    return 1.0f / (1.0f + __expf(-x));
}

// ---------------------------------------------------------------------------
// Hierarchical grid barrier (512 blocks), monotonic counters, threadfence on
// both sides (R5/R7-proven): release = writeback h stores, acquire = inval
// stale L1/L2 lines. 16 groups x 32 arrivals + 16 leaders on one line.
// ---------------------------------------------------------------------------
__device__ __forceinline__ void grid_barrier(int* bar, int step, int bid) {
    __syncthreads();
    if (threadIdx.x == 0) {
        __threadfence();
        const int g = bid & (NGRP - 1);
        int* lcnt = bar + g * 32;
        int* lgen = bar + (NGRP + g) * 32;
        int* gcnt = bar + (2 * NGRP) * 32;
        int* ggen = bar + (2 * NGRP + 1) * 32;
        int a = __hip_atomic_fetch_add(lcnt, 1, __ATOMIC_ACQ_REL, __HIP_MEMORY_SCOPE_AGENT);
        if (a == GSZ * (step + 1) - 1) {
            int b = __hip_atomic_fetch_add(gcnt, 1, __ATOMIC_ACQ_REL, __HIP_MEMORY_SCOPE_AGENT);
            if (b == NGRP * (step + 1) - 1) {
                __hip_atomic_store(ggen, step + 1, __ATOMIC_RELEASE, __HIP_MEMORY_SCOPE_AGENT);
            } else {
                while (__hip_atomic_load(ggen, __ATOMIC_ACQUIRE, __HIP_MEMORY_SCOPE_AGENT) <= step)
                    __builtin_amdgcn_s_sleep(2);
            }
            __hip_atomic_store(lgen, step + 1, __ATOMIC_RELEASE, __HIP_MEMORY_SCOPE_AGENT);
        } else {
            while (__hip_atomic_load(lgen, __ATOMIC_ACQUIRE, __HIP_MEMORY_SCOPE_AGENT) <= step)
                __builtin_amdgcn_s_sleep(2);
        }
        __threadfence();
    }
    __syncthreads();
}

// one k-pair: acc[8 scols] += a.x * w_even + a.y * w_odd
__device__ __forceinline__ void fma_pair(float (&acc)[8], const float2 a,
    const float4 w0, const float4 w1, const float4 w2, const float4 w3)
{
    acc[0] = fmaf(a.x, w0.x, acc[0]); acc[1] = fmaf(a.x, w0.y, acc[1]);
    acc[2] = fmaf(a.x, w0.z, acc[2]); acc[3] = fmaf(a.x, w0.w, acc[3]);
    acc[4] = fmaf(a.x, w1.x, acc[4]); acc[5] = fmaf(a.x, w1.y, acc[5]);
    acc[6] = fmaf(a.x, w1.z, acc[6]); acc[7] = fmaf(a.x, w1.w, acc[7]);
    acc[0] = fmaf(a.y, w2.x, acc[0]); acc[1] = fmaf(a.y, w2.y, acc[1]);
    acc[2] = fmaf(a.y, w2.z, acc[2]); acc[3] = fmaf(a.y, w2.w, acc[3]);
    acc[4] = fmaf(a.y, w3.x, acc[4]); acc[5] = fmaf(a.y, w3.y, acc[5]);
    acc[6] = fmaf(a.y, w3.z, acc[6]); acc[7] = fmaf(a.y, w3.w, acc[7]);
}

// ---------------------------------------------------------------------------
// K-segment GEMM, lane = batch row, 4-deep rolling register prefetch.
// AT: transposed activations, pair p at AT[p*128 + lane*2]. Wp: packed
// weights, 16 contiguous floats per pair (2 k-rows x 8 scols).
// npairs multiple of 4, >= 4. All buffer indices compile-time constant.
// ---------------------------------------------------------------------------
__device__ __forceinline__ void gemm_seg_p(
    const float* __restrict__ AT, const float* __restrict__ Wp,
    int npairs, int lane, float (&acc)[8])
{
    const float* ap = AT + lane * 2;
    float2 a[4];
    float4 w[4][4];
    #pragma unroll
    for (int s = 0; s < 4; ++s) {
        a[s] = *(const float2*)(ap + s * 128);
        w[s][0] = *(const float4*)(Wp + s * 16);
        w[s][1] = *(const float4*)(Wp + s * 16 + 4);
        w[s][2] = *(const float4*)(Wp + s * 16 + 8);
        w[s][3] = *(const float4*)(Wp + s * 16 + 12);
    }
    for (int p = 0; p < npairs; p += 4) {
        const int pn = (p + 4 < npairs) ? (p + 4) : p;   // clamp: last iter reloads self
        const float* apn = ap + pn * 128;
        const float* wpn = Wp + pn * 16;
        #pragma unroll
        for (int s = 0; s < 4; ++s) {
            float2 ac = a[s];
            float4 w0 = w[s][0], w1 = w[s][1], w2 = w[s][2], w3 = w[s][3];
            a[s] = *(const float2*)(apn + s * 128);
            w[s][0] = *(const float4*)(wpn + s * 16);
            w[s][1] = *(const float4*)(wpn + s * 16 + 4);
            w[s][2] = *(const float4*)(wpn + s * 16 + 8);
            w[s][3] = *(const float4*)(wpn + s * 16 + 12);
            fma_pair(acc, ac, w0, w1, w2, w3);
        }
    }
}

// ---------------------------------------------------------------------------
// Persistent 2-layer LSTM, 512 blocks x 512 threads (2 blocks/CU, 16 waves).
// Block owns 2 h-cols (XCD-contiguous): colbase = (bid&7)*128 + (bid>>3)*2.
// 8-wave K-split, LDS reduce, c-states in registers, 1 barrier/step.
// ---------------------------------------------------------------------------
__global__ __launch_bounds__(512, 4)
void lstm_persistent(const float* __restrict__ embT,   // [T][256][64][2]
                     const float* __restrict__ c0_in,
                     const float* __restrict__ c1_in,
                     const float* __restrict__ Wp0e,   // [blk][512][8]
                     const float* __restrict__ Wp0h,   // [blk][1024][8]
                     const float* __restrict__ b0v,
                     const float* __restrict__ Wp1,    // [blk][2048][8]
                     const float* __restrict__ b1v,
                     float* __restrict__ h0T,          // 2 ping-pong slots
                     float* __restrict__ HST,          // [T] slots: h1(t)
                     const float* __restrict__ h1iT,
                     int* bar)
{
    __shared__ float Pred[8][64][8];   // 16 KB
    __shared__ float Sx[64][8];        //  2 KB

    const int tid  = threadIdx.x;
    const int wv   = tid >> 6;
    const int lane = tid & 63;
    const int bid  = blockIdx.x;
    const int colbase = ((bid & 7) << 7) + ((bid >> 3) << 1);

    const float* wp0e = Wp0e + (size_t)bid * (EMB * 8);
    const float* wp0h = Wp0h + (size_t)bid * (HN * 8);
    const float* wp1  = Wp1  + (size_t)bid * (2 * HN * 8);

    // reducer identity: (r = tid>>3, c8 = tid&7), c8 = gate*2 + ci
    const int rc8 = tid & 7;
    const float bf0r = b0v[(rc8 >> 1) * HN + colbase + (rc8 & 1)];
    const float bf1r = b1v[(rc8 >> 1) * HN + colbase + (rc8 & 1)];

    // gate identity (tid<128): r = tid>>1, ci = tid&1
    float c0r = 0.0f, c1r = 0.0f;
    if (tid < 128) {
        c0r = c0_in[(tid >> 1) * HN + colbase + (tid & 1)];
        c1r = c1_in[(tid >> 1) * HN + colbase + (tid & 1)];
    }
    const int hoff = (colbase >> 1) * 128 + tid;   // transposed h slot (tid<128)

    for (int t = 0; t < T_STEPS; ++t) {
        const float* h0prev = h0T + (size_t)((t + 1) & 1) * BHN;
        float*       h0cur  = h0T + (size_t)(t & 1) * BHN;
        const float* h1prev = (t == 0) ? h1iT : HST + (size_t)(t - 1) * BHN;
        float*       h1cur  = HST + (size_t)t * BHN;
        const float* eT     = embT + (size_t)t * (EMB * BATCH);

        // ================= layer 0 =================
        {
            float acc[8] = {};
            const int k0 = wv * 192, k1 = k0 + 192;
            int e1 = (k1 < EMB) ? k1 : EMB;
            if (e1 > k0)
                gemm_seg_p(eT + (k0 >> 1) * 128, wp0e + (size_t)k0 * 8,
                           (e1 - k0) >> 1, lane, acc);
            int hs = (k0 > EMB) ? k0 : EMB;
            if (k1 > hs)
                gemm_seg_p(h0prev + ((hs - EMB) >> 1) * 128, wp0h + (size_t)(hs - EMB) * 8,
                           (k1 - hs) >> 1, lane, acc);
            *(float4*)&Pred[wv][lane][0] = make_float4(acc[0], acc[1], acc[2], acc[3]);
            *(float4*)&Pred[wv][lane][4] = make_float4(acc[4], acc[5], acc[6], acc[7]);
            __syncthreads();
            {
                int r = tid >> 3;
                float s = Pred[0][r][rc8];
                #pragma unroll
                for (int w = 1; w < 8; ++w) s += Pred[w][r][rc8];   // fixed order
                Sx[r][rc8] = s + bf0r;
            }
            __syncthreads();
            if (tid < 128) {
                int r = tid >> 1, ci = tid & 1;
                float fg = sigmoidf_(Sx[r][ci]);
                float ig = sigmoidf_(Sx[r][2 + ci]);
                float og = sigmoidf_(Sx[r][4 + ci]);
                float gg = tanhf(Sx[r][6 + ci]);
                c0r = fg * c0r + ig * gg;
                h0cur[hoff] = og * tanhf(c0r);
            }
        }
        grid_barrier(bar, t, bid);   // h0(t) visible device-wide

        // ================= layer 1 =================
        {
            float acc[8] = {};
            const int k0 = wv << 8;   // 256 k per wave
            const float* at = (wv < 4) ? (h0cur + (k0 >> 1) * 128)
                                       : (h1prev + ((k0 - HN) >> 1) * 128);
            gemm_seg_p(at, wp1 + (size_t)k0 * 8, 128, lane, acc);
            *(float4*)&Pred[wv][lane][0] = make_float4(acc[0], acc[1], acc[2], acc[3]);
            *(float4*)&Pred[wv][lane][4] = make_float4(acc[4], acc[5], acc[6], acc[7]);
            __syncthreads();
            {
                int r = tid >> 3;
                float s = Pred[0][r][rc8];
                #pragma unroll
                for (int w = 1; w < 8; ++w) s += Pred[w][r][rc8];
                Sx[r][rc8] = s + bf1r;
            }
            __syncthreads();
            if (tid < 128) {
                int r = tid >> 1, ci = tid & 1;
                float fg = sigmoidf_(Sx[r][ci]);
                float ig = sigmoidf_(Sx[r][2 + ci]);
                float og = sigmoidf_(Sx[r][4 + ci]);
                float gg = tanhf(Sx[r][6 + ci]);
                c1r = fg * c1r + ig * gg;
                h1cur[hoff] = og * tanhf(c1r);
            }
        }
        // no second barrier: arrival at barrier(t+1) orders h1(t) stores
        // before any block's layer-1(t+1) reads (program-order proof)
    }
}

// ---------------------------------------------------------------------------
// Parallel GEMM: C[M,N] = A[M,K] @ B[K,N]. 128x64 tile, 8x4 micro.
// AMODE 1: A read from transposed [T][K/2][64][2]. CMODE 1: C scattered
// to transposed [T][N/2][64][2].
// ---------------------------------------------------------------------------
template<int AMODE, int CMODE>
__global__ __launch_bounds__(256)
void gemm128(const float* __restrict__ A, const float* __restrict__ B,
             const float* __restrict__ bias, float* __restrict__ C,
             int M, int N, int K, int relu)
{
    __shared__ float As[16][132];
    __shared__ float Bs[16][64];

    const int tid = threadIdx.x;
    const int tx = tid & 15, ty = tid >> 4;
    const int m0 = blockIdx.y << 7, n0 = blockIdx.x << 6;
    float acc[8][4] = {};

    for (int kk = 0; kk < K; kk += 16) {
        if (AMODE == 0) {
            #pragma unroll
            for (int i = 0; i < 8; ++i) {
                int e = tid + (i << 8);
                int r = e >> 4, k = e & 15;
                As[k][r] = A[(size_t)(m0 + r) * K + kk + k];
            }
        } else {
            #pragma unroll
            for (int i = 0; i < 8; ++i) {
                int e = tid + (i << 8);
                int k = e >> 7, rr = e & 127;
                int gm = m0 + rr, tt = gm >> 6, b = gm & 63;
                As[k][rr] = A[(size_t)tt * BHN + ((kk + k) >> 1) * 128 + b * 2 + ((kk + k) & 1)];
            }
        }
        #pragma unroll
        for (int i = 0; i < 4; ++i) {
            int e = tid + (i << 8);
            int r = e >> 6, c = e & 63;
            Bs[r][c] = B[(size_t)(kk + r) * N + n0 + c];
        }
        __syncthreads();
        #pragma unroll
        for (int k = 0; k < 16; ++k) {
            float4 a0 = *(const float4*)&As[k][(ty << 3)];
            float4 a1 = *(const float4*)&As[k][(ty << 3) + 4];
            float4 b4 = *(const float4*)&Bs[k][(tx << 2)];
            float a[8] = {a0.x, a0.y, a0.z, a0.w, a1.x, a1.y, a1.z, a1.w};
            float b[4] = {b4.x, b4.y, b4.z, b4.w};
            #pragma unroll
            for (int i = 0; i < 8; ++i)
                #pragma unroll
                for (int j = 0; j < 4; ++j)
                    acc[i][j] = fmaf(a[i], b[j], acc[i][j]);
        }
        __syncthreads();
    }

    if (CMODE == 0) {
        #pragma unroll
        for (int i = 0; i < 8; ++i) {
            int gm = m0 + (ty << 3) + i;
            float4 o;
            float* op = (float*)&o;
            #pragma unroll
            for (int j = 0; j < 4; ++j) {
                int gn = n0 + (tx << 2) + j;
                float v = acc[i][j] + (bias ? bias[gn] : 0.0f);
                if (relu) v = fmaxf(v, 0.0f);
                op[j] = v;
            }
            *(float4*)&C[(size_t)gm * N + n0 + (tx << 2)] = o;
        }
    } else {
        #pragma unroll
        for (int i = 0; i < 8; ++i) {
            int gm = m0 + (ty << 3) + i;
            int tt = gm >> 6, b = gm & 63;
            float* base = C + (size_t)tt * (EMB * BATCH) + b * 2;
            int gn = n0 + (tx << 2);
            *(float2*)(base + (gn >> 1) * 128) = make_float2(acc[i][0], acc[i][1]);
            *(float2*)(base + ((gn + 2) >> 1) * 128) = make_float2(acc[i][2], acc[i][3]);
        }
    }
}

// pack Wsrc[kbeg+k][g*HN + colbase(b) + ci] -> Wp[b][k][g*2+ci], k < 2^kshift
__global__ __launch_bounds__(256)
void pack_w(const float* __restrict__ Wsrc, float* __restrict__ Wp,
            int kbeg, int kshift)
{
    int idx = blockIdx.x * 256 + threadIdx.x;
    int c8 = idx & 7;
    int k  = (idx >> 3) & ((1 << kshift) - 1);
    int b  = idx >> (3 + kshift);
    int colbase = ((b & 7) << 7) + ((b >> 3) << 1);
    Wp[idx] = Wsrc[(size_t)(kbeg + k) * SDIM + (c8 >> 1) * HN + colbase + (c8 & 1)];
}

// zero barrier + transpose initial h states
__global__ __launch_bounds__(256)
void init_misc(const float* __restrict__ h0_in, const float* __restrict__ h1_in,
               float* __restrict__ h0T, float* __restrict__ h1iT, int* bar) {
    int i = blockIdx.x * 256 + threadIdx.x;
    if (i < 2048) bar[i] = 0;
    if (i < BHN) {
        int b = i >> 10, col = i & 1023;
        int tj = (col >> 1) * 128 + b * 2 + (col & 1);
        h0T[BHN + tj] = h0_in[i];   // slot 1 = h0(-1)
        h1iT[tj] = h1_in[i];
    }
}

extern "C" void kernel_launch(void* const* d_in, const int* in_sizes, int n_in,
                              void* d_out, int out_size, void* d_ws, size_t ws_size,
                              hipStream_t stream) {
    const float* inputs     = (const float*)d_in[0];
    const float* h0_in      = (const float*)d_in[1];
    const float* c0_in      = (const float*)d_in[2];
    const float* h1_in      = (const float*)d_in[3];
    const float* c1_in      = (const float*)d_in[4];
    const float* emb_matrix = (const float*)d_in[5];
    const float* lstm_w0    = (const float*)d_in[6];
    const float* lstm_b0    = (const float*)d_in[7];
    const float* lstm_w1    = (const float*)d_in[8];
    const float* lstm_b1    = (const float*)d_in[9];
    const float* out_w0     = (const float*)d_in[10];
    const float* out_b0     = (const float*)d_in[11];
    const float* out_w1     = (const float*)d_in[12];
    const float* out_b1     = (const float*)d_in[13];
    float* logits = (float*)d_out;

    const int MB = T_STEPS * BATCH;  // 12800

    // workspace (floats), ~130 MB:
    float* ws   = (float*)d_ws;
    float* embT = ws;                                   //  6,553,600
    float* Wp0h = embT + (size_t)MB * EMB;              //  4,194,304
    float* Wp1  = Wp0h + (size_t)NBLK * HN * 8;         //  8,388,608
    float* HST  = Wp1  + (size_t)NBLK * 2 * HN * 8;     // 13,107,200
    float* h0T  = HST  + (size_t)T_STEPS * BHN;         //    131,072
    float* h1iT = h0T  + 2 * (size_t)BHN;               //     65,536
    int*   bar  = (int*)(h1iT + (size_t)BHN);           //      2,048
    // hid (12800x1024) aliases embT+Wp0h+head of Wp1 — all dead post-recurrence
    float* hid  = ws;
    // Wp0e (512x512x8 = 2,097,152 floats) lives in d_out (13.1 MB),
    // dead before the final logits GEMM writes d_out.
    float* Wp0e = (float*)d_out;

    init_misc<<<dim3(256), 256, 0, stream>>>(h0_in, h1_in, h0T, h1iT, bar);
    pack_w<<<dim3(8192),  256, 0, stream>>>(lstm_w0, Wp0e, 0,   9);   // emb part
    pack_w<<<dim3(16384), 256, 0, stream>>>(lstm_w0, Wp0h, 512, 10);  // h part
    pack_w<<<dim3(32768), 256, 0, stream>>>(lstm_w1, Wp1,  0,   11);

    // embT = (inputs @ emb_matrix) transposed-interleaved
    gemm128<0, 1><<<dim3(EMB / 64, MB / 128), 256, 0, stream>>>(
        inputs, emb_matrix, nullptr, embT, MB, EMB, VOCAB, 0);

    lstm_persistent<<<dim3(NBLK), 512, 0, stream>>>(
        embT, c0_in, c1_in, Wp0e, Wp0h, lstm_b0, Wp1, lstm_b1,
        h0T, HST, h1iT, bar);

    // hid = relu(HS @ out_w0 + out_b0), A from transposed HST
    gemm128<1, 0><<<dim3(ON_ / 64, MB / 128), 256, 0, stream>>>(
        HST, out_w0, out_b0, hid, MB, ON_, HN, 1);

    // logits = hid @ out_w1 + out_b1 (overwrites Wp0e region of d_out)
    gemm128<0, 0><<<dim3(VOCAB / 64, MB / 128), 256, 0, stream>>>(
        hid, out_w1, out_b1, logits, MB, VOCAB, ON_, 0);
}

// Round 9
// 61514.941 us; speedup vs baseline: 1.0177x; 1.0177x over previous
//
#include <hip/hip_runtime.h>
#include <math.h>

#define T_STEPS 200
#define BATCH   64
#define VOCAB   256
#define EMB     512
#define HN      1024
#define ON_     1024
#define SDIM    4096   // 4*HN
#define NBLK    512
#define BHN     (BATCH * HN)   // 65536
#define NGRP    16
#define GSZ     (NBLK / NGRP)  // 32

__device__ __forceinline__ float sigmoidf_(float x) {
    return 1.0f / (1.0f + __expf(-x));
}

// ---------------------------------------------------------------------------
// Hierarchical grid barrier (512 blocks), monotonic counters, threadfence on
// both sides (R5/R7-proven): release = writeback h stores, acquire = inval
// stale L1/L2 lines. 16 groups x 32 arrivals + 16 leaders on one line.
// ---------------------------------------------------------------------------
__device__ __forceinline__ void grid_barrier(int* bar, int step, int bid) {
    __syncthreads();
    if (threadIdx.x == 0) {
        __threadfence();
        const int g = bid & (NGRP - 1);
        int* lcnt = bar + g * 32;
        int* lgen = bar + (NGRP + g) * 32;
        int* gcnt = bar + (2 * NGRP) * 32;
        int* ggen = bar + (2 * NGRP + 1) * 32;
        int a = __hip_atomic_fetch_add(lcnt, 1, __ATOMIC_ACQ_REL, __HIP_MEMORY_SCOPE_AGENT);
        if (a == GSZ * (step + 1) - 1) {
            int b = __hip_atomic_fetch_add(gcnt, 1, __ATOMIC_ACQ_REL, __HIP_MEMORY_SCOPE_AGENT);
            if (b == NGRP * (step + 1) - 1) {
                __hip_atomic_store(ggen, step + 1, __ATOMIC_RELEASE, __HIP_MEMORY_SCOPE_AGENT);
            } else {
                while (__hip_atomic_load(ggen, __ATOMIC_ACQUIRE, __HIP_MEMORY_SCOPE_AGENT) <= step)
                    __builtin_amdgcn_s_sleep(2);
            }
            __hip_atomic_store(lgen, step + 1, __ATOMIC_RELEASE, __HIP_MEMORY_SCOPE_AGENT);
        } else {
            while (__hip_atomic_load(lgen, __ATOMIC_ACQUIRE, __HIP_MEMORY_SCOPE_AGENT) <= step)
                __builtin_amdgcn_s_sleep(2);
        }
        __threadfence();
    }
    __syncthreads();
}

// one k-pair: acc[8 scols] += a.x * w_even + a.y * w_odd
__device__ __forceinline__ void fma_pair(float (&acc)[8], const float2 a,
    const float4 w0, const float4 w1, const float4 w2, const float4 w3)
{
    acc[0] = fmaf(a.x, w0.x, acc[0]); acc[1] = fmaf(a.x, w0.y, acc[1]);
    acc[2] = fmaf(a.x, w0.z, acc[2]); acc[3] = fmaf(a.x, w0.w, acc[3]);
    acc[4] = fmaf(a.x, w1.x, acc[4]); acc[5] = fmaf(a.x, w1.y, acc[5]);
    acc[6] = fmaf(a.x, w1.z, acc[6]); acc[7] = fmaf(a.x, w1.w, acc[7]);
    acc[0] = fmaf(a.y, w2.x, acc[0]); acc[1] = fmaf(a.y, w2.y, acc[1]);
    acc[2] = fmaf(a.y, w2.z, acc[2]); acc[3] = fmaf(a.y, w2.w, acc[3]);
    acc[4] = fmaf(a.y, w3.x, acc[4]); acc[5] = fmaf(a.y, w3.y, acc[5]);
    acc[6] = fmaf(a.y, w3.z, acc[6]); acc[7] = fmaf(a.y, w3.w, acc[7]);
}

// ---------------------------------------------------------------------------
// K-segment GEMM, lane = batch row, 4-deep rolling register prefetch.
// AT: transposed activations, pair p at AT[p*128 + lane*2]. Wp: packed
// weights, 16 contiguous floats per pair (2 k-rows x 8 scols).
// npairs multiple of 4, >= 4. All buffer indices compile-time constant.
// ---------------------------------------------------------------------------
__device__ __forceinline__ void gemm_seg_p(
    const float* __restrict__ AT, const float* __restrict__ Wp,
    int npairs, int lane, float (&acc)[8])
{
    const float* ap = AT + lane * 2;
    float2 a[4];
    float4 w[4][4];
    #pragma unroll
    for (int s = 0; s < 4; ++s) {
        a[s] = *(const float2*)(ap + s * 128);
        w[s][0] = *(const float4*)(Wp + s * 16);
        w[s][1] = *(const float4*)(Wp + s * 16 + 4);
        w[s][2] = *(const float4*)(Wp + s * 16 + 8);
        w[s][3] = *(const float4*)(Wp + s * 16 + 12);
    }
    for (int p = 0; p < npairs; p += 4) {
        const int pn = (p + 4 < npairs) ? (p + 4) : p;   // clamp: last iter reloads self
        const float* apn = ap + pn * 128;
        const float* wpn = Wp + pn * 16;
        #pragma unroll
        for (int s = 0; s < 4; ++s) {
            float2 ac = a[s];
            float4 w0 = w[s][0], w1 = w[s][1], w2 = w[s][2], w3 = w[s][3];
            a[s] = *(const float2*)(apn + s * 128);
            w[s][0] = *(const float4*)(wpn + s * 16);
            w[s][1] = *(const float4*)(wpn + s * 16 + 4);
            w[s][2] = *(const float4*)(wpn + s * 16 + 8);
            w[s][3] = *(const float4*)(wpn + s * 16 + 12);
            fma_pair(acc, ac, w0, w1, w2, w3);
        }
    }
}

// ---------------------------------------------------------------------------
// Persistent 2-layer LSTM, 512 blocks x 512 threads (2 blocks/CU, 16 waves).
// Block owns 2 h-cols (XCD-contiguous): colbase = (bid&7)*128 + (bid>>3)*2.
// 8-wave K-split, LDS reduce, c-states in registers, 1 barrier/step.
// ---------------------------------------------------------------------------
__global__ __launch_bounds__(512, 4)
void lstm_persistent(const float* __restrict__ embT,   // [T][256][64][2]
                     const float* __restrict__ c0_in,
                     const float* __restrict__ c1_in,
                     const float* __restrict__ Wp0e,   // [blk][512][8]
                     const float* __restrict__ Wp0h,   // [blk][1024][8]
                     const float* __restrict__ b0v,
                     const float* __restrict__ Wp1,    // [blk][2048][8]
                     const float* __restrict__ b1v,
                     float* __restrict__ h0T,          // 2 ping-pong slots
                     float* __restrict__ HST,          // [T] slots: h1(t)
                     const float* __restrict__ h1iT,
                     int* bar)
{
    __shared__ float Pred[8][64][8];   // 16 KB
    __shared__ float Sx[64][8];        //  2 KB

    const int tid  = threadIdx.x;
    const int wv   = tid >> 6;
    const int lane = tid & 63;
    const int bid  = blockIdx.x;
    const int colbase = ((bid & 7) << 7) + ((bid >> 3) << 1);

    const float* wp0e = Wp0e + (size_t)bid * (EMB * 8);
    const float* wp0h = Wp0h + (size_t)bid * (HN * 8);
    const float* wp1  = Wp1  + (size_t)bid * (2 * HN * 8);

    // reducer identity: (r = tid>>3, c8 = tid&7), c8 = gate*2 + ci
    const int rc8 = tid & 7;
    const float bf0r = b0v[(rc8 >> 1) * HN + colbase + (rc8 & 1)];
    const float bf1r = b1v[(rc8 >> 1) * HN + colbase + (rc8 & 1)];

    // gate identity (tid<128): r = tid>>1, ci = tid&1
    float c0r = 0.0f, c1r = 0.0f;
    if (tid < 128) {
        c0r = c0_in[(tid >> 1) * HN + colbase + (tid & 1)];
        c1r = c1_in[(tid >> 1) * HN + colbase + (tid & 1)];
    }
    const int hoff = (colbase >> 1) * 128 + tid;   // transposed h slot (tid<128)

    for (int t = 0; t < T_STEPS; ++t) {
        const float* h0prev = h0T + (size_t)((t + 1) & 1) * BHN;
        float*       h0cur  = h0T + (size_t)(t & 1) * BHN;
        const float* h1prev = (t == 0) ? h1iT : HST + (size_t)(t - 1) * BHN;
        float*       h1cur  = HST + (size_t)t * BHN;
        const float* eT     = embT + (size_t)t * (EMB * BATCH);

        // ================= layer 0 =================
        {
            float acc[8] = {};
            const int k0 = wv * 192, k1 = k0 + 192;
            int e1 = (k1 < EMB) ? k1 : EMB;
            if (e1 > k0)
                gemm_seg_p(eT + (k0 >> 1) * 128, wp0e + (size_t)k0 * 8,
                           (e1 - k0) >> 1, lane, acc);
            int hs = (k0 > EMB) ? k0 : EMB;
            if (k1 > hs)
                gemm_seg_p(h0prev + ((hs - EMB) >> 1) * 128, wp0h + (size_t)(hs - EMB) * 8,
                           (k1 - hs) >> 1, lane, acc);
            *(float4*)&Pred[wv][lane][0] = make_float4(acc[0], acc[1], acc[2], acc[3]);
            *(float4*)&Pred[wv][lane][4] = make_float4(acc[4], acc[5], acc[6], acc[7]);
            __syncthreads();
            {
                int r = tid >> 3;
                float s = Pred[0][r][rc8];
                #pragma unroll
                for (int w = 1; w < 8; ++w) s += Pred[w][r][rc8];   // fixed order
                Sx[r][rc8] = s + bf0r;
            }
            __syncthreads();
            if (tid < 128) {
                int r = tid >> 1, ci = tid & 1;
                float fg = sigmoidf_(Sx[r][ci]);
                float ig = sigmoidf_(Sx[r][2 + ci]);
                float og = sigmoidf_(Sx[r][4 + ci]);
                float gg = tanhf(Sx[r][6 + ci]);
                c0r = fg * c0r + ig * gg;
                h0cur[hoff] = og * tanhf(c0r);
            }
        }
        grid_barrier(bar, t, bid);   // h0(t) visible device-wide

        // ================= layer 1 =================
        {
            float acc[8] = {};
            const int k0 = wv << 8;   // 256 k per wave
            const float* at = (wv < 4) ? (h0cur + (k0 >> 1) * 128)
                                       : (h1prev + ((k0 - HN) >> 1) * 128);
            gemm_seg_p(at, wp1 + (size_t)k0 * 8, 128, lane, acc);
            *(float4*)&Pred[wv][lane][0] = make_float4(acc[0], acc[1], acc[2], acc[3]);
            *(float4*)&Pred[wv][lane][4] = make_float4(acc[4], acc[5], acc[6], acc[7]);
            __syncthreads();
            {
                int r = tid >> 3;
                float s = Pred[0][r][rc8];
                #pragma unroll
                for (int w = 1; w < 8; ++w) s += Pred[w][r][rc8];
                Sx[r][rc8] = s + bf1r;
            }
            __syncthreads();
            if (tid < 128) {
                int r = tid >> 1, ci = tid & 1;
                float fg = sigmoidf_(Sx[r][ci]);
                float ig = sigmoidf_(Sx[r][2 + ci]);
                float og = sigmoidf_(Sx[r][4 + ci]);
                float gg = tanhf(Sx[r][6 + ci]);
                c1r = fg * c1r + ig * gg;
                h1cur[hoff] = og * tanhf(c1r);
            }
        }
        // no second barrier: arrival at barrier(t+1) orders h1(t) stores
        // before any block's layer-1(t+1) reads (program-order proof)
    }
}

// ---------------------------------------------------------------------------
// Parallel GEMM: C[M,N] = A[M,K] @ B[K,N]. 128x64 tile, 8x4 micro.
// AMODE 1: A read from transposed [T][K/2][64][2]. CMODE 1: C scattered
// to transposed [T][N/2][64][2].
// ---------------------------------------------------------------------------
template<int AMODE, int CMODE>
__global__ __launch_bounds__(256)
void gemm128(const float* __restrict__ A, const float* __restrict__ B,
             const float* __restrict__ bias, float* __restrict__ C,
             int M, int N, int K, int relu)
{
    __shared__ float As[16][132];
    __shared__ float Bs[16][64];

    const int tid = threadIdx.x;
    const int tx = tid & 15, ty = tid >> 4;
    const int m0 = blockIdx.y << 7, n0 = blockIdx.x << 6;
    float acc[8][4] = {};

    for (int kk = 0; kk < K; kk += 16) {
        if (AMODE == 0) {
            #pragma unroll
            for (int i = 0; i < 8; ++i) {
                int e = tid + (i << 8);
                int r = e >> 4, k = e & 15;
                As[k][r] = A[(size_t)(m0 + r) * K + kk + k];
            }
        } else {
            #pragma unroll
            for (int i = 0; i < 8; ++i) {
                int e = tid + (i << 8);
                int k = e >> 7, rr = e & 127;
                int gm = m0 + rr, tt = gm >> 6, b = gm & 63;
                As[k][rr] = A[(size_t)tt * BHN + ((kk + k) >> 1) * 128 + b * 2 + ((kk + k) & 1)];
            }
        }
        #pragma unroll
        for (int i = 0; i < 4; ++i) {
            int e = tid + (i << 8);
            int r = e >> 6, c = e & 63;
            Bs[r][c] = B[(size_t)(kk + r) * N + n0 + c];
        }
        __syncthreads();
        #pragma unroll
        for (int k = 0; k < 16; ++k) {
            float4 a0 = *(const float4*)&As[k][(ty << 3)];
            float4 a1 = *(const float4*)&As[k][(ty << 3) + 4];
            float4 b4 = *(const float4*)&Bs[k][(tx << 2)];
            float a[8] = {a0.x, a0.y, a0.z, a0.w, a1.x, a1.y, a1.z, a1.w};
            float b[4] = {b4.x, b4.y, b4.z, b4.w};
            #pragma unroll
            for (int i = 0; i < 8; ++i)
                #pragma unroll
                for (int j = 0; j < 4; ++j)
                    acc[i][j] = fmaf(a[i], b[j], acc[i][j]);
        }
        __syncthreads();
    }

    if (CMODE == 0) {
        #pragma unroll
        for (int i = 0; i < 8; ++i) {
            int gm = m0 + (ty << 3) + i;
            float4 o;
            float* op = (float*)&o;
            #pragma unroll
            for (int j = 0; j < 4; ++j) {
                int gn = n0 + (tx << 2) + j;
                float v = acc[i][j] + (bias ? bias[gn] : 0.0f);
                if (relu) v = fmaxf(v, 0.0f);
                op[j] = v;
            }
            *(float4*)&C[(size_t)gm * N + n0 + (tx << 2)] = o;
        }
    } else {
        #pragma unroll
        for (int i = 0; i < 8; ++i) {
            int gm = m0 + (ty << 3) + i;
            int tt = gm >> 6, b = gm & 63;
            float* base = C + (size_t)tt * (EMB * BATCH) + b * 2;
            int gn = n0 + (tx << 2);
            *(float2*)(base + (gn >> 1) * 128) = make_float2(acc[i][0], acc[i][1]);
            *(float2*)(base + ((gn + 2) >> 1) * 128) = make_float2(acc[i][2], acc[i][3]);
        }
    }
}

// pack Wsrc[kbeg+k][g*HN + colbase(b) + ci] -> Wp[b][k][g*2+ci], k < 2^kshift
__global__ __launch_bounds__(256)
void pack_w(const float* __restrict__ Wsrc, float* __restrict__ Wp,
            int kbeg, int kshift)
{
    int idx = blockIdx.x * 256 + threadIdx.x;
    int c8 = idx & 7;
    int k  = (idx >> 3) & ((1 << kshift) - 1);
    int b  = idx >> (3 + kshift);
    int colbase = ((b & 7) << 7) + ((b >> 3) << 1);
    Wp[idx] = Wsrc[(size_t)(kbeg + k) * SDIM + (c8 >> 1) * HN + colbase + (c8 & 1)];
}

// zero barrier + transpose initial h states
__global__ __launch_bounds__(256)
void init_misc(const float* __restrict__ h0_in, const float* __restrict__ h1_in,
               float* __restrict__ h0T, float* __restrict__ h1iT, int* bar) {
    int i = blockIdx.x * 256 + threadIdx.x;
    if (i < 2048) bar[i] = 0;
    if (i < BHN) {
        int b = i >> 10, col = i & 1023;
        int tj = (col >> 1) * 128 + b * 2 + (col & 1);
        h0T[BHN + tj] = h0_in[i];   // slot 1 = h0(-1)
        h1iT[tj] = h1_in[i];
    }
}

extern "C" void kernel_launch(void* const* d_in, const int* in_sizes, int n_in,
                              void* d_out, int out_size, void* d_ws, size_t ws_size,
                              hipStream_t stream) {
    const float* inputs     = (const float*)d_in[0];
    const float* h0_in      = (const float*)d_in[1];
    const float* c0_in      = (const float*)d_in[2];
    const float* h1_in      = (const float*)d_in[3];
    const float* c1_in      = (const float*)d_in[4];
    const float* emb_matrix = (const float*)d_in[5];
    const float* lstm_w0    = (const float*)d_in[6];
    const float* lstm_b0    = (const float*)d_in[7];
    const float* lstm_w1    = (const float*)d_in[8];
    const float* lstm_b1    = (const float*)d_in[9];
    const float* out_w0     = (const float*)d_in[10];
    const float* out_b0     = (const float*)d_in[11];
    const float* out_w1     = (const float*)d_in[12];
    const float* out_b1     = (const float*)d_in[13];
    float* logits = (float*)d_out;

    const int MB = T_STEPS * BATCH;  // 12800

    // workspace (floats), ~130 MB:
    float* ws   = (float*)d_ws;
    float* embT = ws;                                   //  6,553,600
    float* Wp0h = embT + (size_t)MB * EMB;              //  4,194,304
    float* Wp1  = Wp0h + (size_t)NBLK * HN * 8;         //  8,388,608
    float* HST  = Wp1  + (size_t)NBLK * 2 * HN * 8;     // 13,107,200
    float* h0T  = HST  + (size_t)T_STEPS * BHN;         //    131,072
    float* h1iT = h0T  + 2 * (size_t)BHN;               //     65,536
    int*   bar  = (int*)(h1iT + (size_t)BHN);           //      2,048
    // hid (12800x1024) aliases embT+Wp0h+head of Wp1 — all dead post-recurrence
    float* hid  = ws;
    // Wp0e (512x512x8 = 2,097,152 floats) lives in d_out (13.1 MB),
    // dead before the final logits GEMM writes d_out.
    float* Wp0e = (float*)d_out;

    init_misc<<<dim3(256), 256, 0, stream>>>(h0_in, h1_in, h0T, h1iT, bar);
    pack_w<<<dim3(8192),  256, 0, stream>>>(lstm_w0, Wp0e, 0,   9);   // emb part
    pack_w<<<dim3(16384), 256, 0, stream>>>(lstm_w0, Wp0h, 512, 10);  // h part
    pack_w<<<dim3(32768), 256, 0, stream>>>(lstm_w1, Wp1,  0,   11);

    // embT = (inputs @ emb_matrix) transposed-interleaved
    gemm128<0, 1><<<dim3(EMB / 64, MB / 128), 256, 0, stream>>>(
        inputs, emb_matrix, nullptr, embT, MB, EMB, VOCAB, 0);

    lstm_persistent<<<dim3(NBLK), 512, 0, stream>>>(
        embT, c0_in, c1_in, Wp0e, Wp0h, lstm_b0, Wp1, lstm_b1,
        h0T, HST, h1iT, bar);

    // hid = relu(HS @ out_w0 + out_b0), A from transposed HST
    gemm128<1, 0><<<dim3(ON_ / 64, MB / 128), 256, 0, stream>>>(
        HST, out_w0, out_b0, hid, MB, ON_, HN, 1);

    // logits = hid @ out_w1 + out_b1 (overwrites Wp0e region of d_out)
    gemm128<0, 0><<<dim3(VOCAB / 64, MB / 128), 256, 0, stream>>>(
        hid, out_w1, out_b1, logits, MB, VOCAB, ON_, 0);
}

// Round 10
// 13066.176 us; speedup vs baseline: 4.7914x; 4.7080x over previous
//
#include <hip/hip_runtime.h>
#include <hip/hip_bf16.h>
#include <math.h>

#define T_STEPS 200
#define BATCH   64
#define VOCAB   256
#define EMB     512
#define HN      1024
#define ON_     1024
#define SDIM    4096
#define NBLK    256
#define BHN     65536          // floats per h vector (64 x 1024)
#define HSLOT   65536
#define ESLOT   32768          // floats per emb step (64 x 512)
#define NGRP    8
#define GSZ     32
#define GTOT    (T_STEPS * 28) // 12 L0-tiles + 16 L1-tiles per step
#define W1SPLIT 156

typedef __attribute__((address_space(1))) const void gas_t;
typedef __attribute__((address_space(3))) void las_t;
#define GLDS(gp, lp) __builtin_amdgcn_global_load_lds((gas_t*)(gp), (las_t*)(lp), 16, 0, 0)
#define WAITVM(n) asm volatile("s_waitcnt vmcnt(" #n ")" ::: "memory")
#define LGKM_BAR() do { asm volatile("s_waitcnt lgkmcnt(0)" ::: "memory"); \
    __builtin_amdgcn_s_barrier(); asm volatile("" ::: "memory"); } while (0)

__device__ __forceinline__ float sigmoidf_(float x) {
    return 1.0f / (1.0f + __expf(-x));
}

// transposed activation layout: pair-block of 512B, rows {2q,2q+1} then {2q+32,2q+33}
__device__ __forceinline__ int tidx(int b, int k) {
    return ((k >> 1) << 7) + ((b >> 5) << 6) + (((b & 31) >> 1) << 2) + ((b & 1) << 1) + (k & 1);
}

// ---------------------------------------------------------------------------
// Grid barrier: waves 0-3 drain their stores (h writes), raw s_barrier keeps
// waves 4-7's W-ring loads in flight. tid0 fence+atomics = R5/R7-proven.
// ---------------------------------------------------------------------------
__device__ __forceinline__ void grid_barrier(int* bar, int step, int bid, int tid, int wv) {
    if (wv < 4) { WAITVM(0); }
    asm volatile("s_waitcnt lgkmcnt(0)" ::: "memory");
    __builtin_amdgcn_s_barrier();
    if (tid == 0) {
        __threadfence();
        const int gidx = bid & (NGRP - 1);
        int* lcnt = bar + gidx * 32;
        int* lgen = bar + (NGRP + gidx) * 32;
        int* gcnt = bar + (2 * NGRP) * 32;
        int* ggen = bar + (2 * NGRP + 1) * 32;
        int a = __hip_atomic_fetch_add(lcnt, 1, __ATOMIC_ACQ_REL, __HIP_MEMORY_SCOPE_AGENT);
        if (a == GSZ * (step + 1) - 1) {
            int b = __hip_atomic_fetch_add(gcnt, 1, __ATOMIC_ACQ_REL, __HIP_MEMORY_SCOPE_AGENT);
            if (b == NGRP * (step + 1) - 1) {
                __hip_atomic_store(ggen, step + 1, __ATOMIC_RELEASE, __HIP_MEMORY_SCOPE_AGENT);
            } else {
                while (__hip_atomic_load(ggen, __ATOMIC_ACQUIRE, __HIP_MEMORY_SCOPE_AGENT) <= step)
                    __builtin_amdgcn_s_sleep(2);
            }
            __hip_atomic_store(lgen, step + 1, __ATOMIC_RELEASE, __HIP_MEMORY_SCOPE_AGENT);
        } else {
            while (__hip_atomic_load(lgen, __ATOMIC_ACQUIRE, __HIP_MEMORY_SCOPE_AGENT) <= step)
                __builtin_amdgcn_s_sleep(2);
        }
        __threadfence();
    }
    asm volatile("" ::: "memory");
    __builtin_amdgcn_s_barrier();
    asm volatile("" ::: "memory");
}

// ---------------------------------------------------------------------------
// Persistent 2-layer LSTM. 256 blocks x 512 thr, block owns 4 h-cols
// (XCD-contiguous). Waves 0-3: A-staging (vmcnt(0)/tile). Waves 4-7:
// W-staging, 5-slot ring, 4-tile lookahead, vmcnt(6), never drained.
// ---------------------------------------------------------------------------
__global__ __launch_bounds__(512, 2)
void lstm_persistent(const float* __restrict__ embT,
                     const float* __restrict__ c0_in, const float* __restrict__ c1_in,
                     const float* __restrict__ Wp0,
                     const float* __restrict__ Wp1a, const float* __restrict__ Wp1b,
                     const float* __restrict__ b0v, const float* __restrict__ b1v,
                     float* __restrict__ h0T, float* __restrict__ HST,
                     const float* __restrict__ h1iT, int* bar)
{
    __shared__ float  Ab[2][8192];        // 64 KB  A double-buffer (tile = 128k x 64b)
    __shared__ float  Wr[5][2048];        // 40 KB  W ring (tile = 128k x 16c)
    __shared__ float4 Pred4[8][64][5];    // 40 KB  (pad 5 -> optimal 8-beat b128)
    __shared__ float  Sx[16][66];         //  4 KB

    const int tid  = threadIdx.x;
    const int wv   = tid >> 6;
    const int lane = tid & 63;
    const int q    = lane & 15;
    const int c0   = (lane >> 4) << 2;
    const int bid  = blockIdx.x;
    const int colbase = ((bid & 7) << 7) + ((bid >> 3) << 2);

    const float* wp0 = Wp0 + (size_t)bid * ((EMB + HN) * 16);
    const float* wp1 = (bid < W1SPLIT) ? Wp1a + (size_t)bid * (2 * HN * 16)
                                       : Wp1b + (size_t)(bid - W1SPLIT) * (2 * HN * 16);

    float bf0[4], bf1[4], c0r = 0.f, c1r = 0.f;
    if (tid < 256) {
        int gr = tid >> 2, gi = tid & 3;
        c0r = c0_in[gr * HN + colbase + gi];
        c1r = c1_in[gr * HN + colbase + gi];
        #pragma unroll
        for (int gk = 0; gk < 4; ++gk) {
            bf0[gk] = b0v[gk * HN + colbase + gi];
            bf1[gk] = b1v[gk * HN + colbase + gi];
        }
    }

    int g = 0, g5 = 0, buf = 0;

    auto issueW = [&](int gt, int slot) {
        if (gt >= GTOT) return;
        int g28 = gt % 28;
        const float* s = (g28 < 12) ? wp0 + (size_t)g28 * 2048
                                    : wp1 + (size_t)(g28 - 12) * 2048;
        const int j0 = (wv - 4) << 1;
        #pragma unroll
        for (int jj = 0; jj < 2; ++jj) {
            int c = j0 + jj;
            GLDS(s + c * 256 + (lane << 2), &Wr[slot][c << 8]);
        }
    };
    auto issueA = [&](const float* src, int nb) {
        #pragma unroll
        for (int i = 0; i < 8; ++i) {
            int c = (wv << 3) + i;
            GLDS(src + c * 256 + (lane << 2), &Ab[nb][c << 8]);
        }
    };
    auto computeTile = [&](int nb, int wsl, float (&acc)[4][4]) {
        #pragma unroll
        for (int pp = 0; pp < 8; ++pp) {
            const float* ab = &Ab[nb][(((wv << 3) + pp) << 7) + (q << 2)];
            float4 alo = *(const float4*)ab;          // rows 2q,2q+1  x k0,k1
            float4 ahi = *(const float4*)(ab + 64);   // rows 2q+32,2q+33
            const float* wb = &Wr[wsl][(wv << 8) + (pp << 5) + c0];
            float4 w0 = *(const float4*)wb;           // k0, 4 scols
            float4 w1 = *(const float4*)(wb + 16);    // k1
            // k0 (same per-cell order as R5: k ascending)
            acc[0][0]=fmaf(alo.x,w0.x,acc[0][0]); acc[0][1]=fmaf(alo.x,w0.y,acc[0][1]);
            acc[0][2]=fmaf(alo.x,w0.z,acc[0][2]); acc[0][3]=fmaf(alo.x,w0.w,acc[0][3]);
            acc[1][0]=fmaf(alo.z,w0.x,acc[1][0]); acc[1][1]=fmaf(alo.z,w0.y,acc[1][1]);
            acc[1][2]=fmaf(alo.z,w0.z,acc[1][2]); acc[1][3]=fmaf(alo.z,w0.w,acc[1][3]);
            acc[2][0]=fmaf(ahi.x,w0.x,acc[2][0]); acc[2][1]=fmaf(ahi.x,w0.y,acc[2][1]);
            acc[2][2]=fmaf(ahi.x,w0.z,acc[2][2]); acc[2][3]=fmaf(ahi.x,w0.w,acc[2][3]);
            acc[3][0]=fmaf(ahi.z,w0.x,acc[3][0]); acc[3][1]=fmaf(ahi.z,w0.y,acc[3][1]);
            acc[3][2]=fmaf(ahi.z,w0.z,acc[3][2]); acc[3][3]=fmaf(ahi.z,w0.w,acc[3][3]);
            // k1
            acc[0][0]=fmaf(alo.y,w1.x,acc[0][0]); acc[0][1]=fmaf(alo.y,w1.y,acc[0][1]);
            acc[0][2]=fmaf(alo.y,w1.z,acc[0][2]); acc[0][3]=fmaf(alo.y,w1.w,acc[0][3]);
            acc[1][0]=fmaf(alo.w,w1.x,acc[1][0]); acc[1][1]=fmaf(alo.w,w1.y,acc[1][1]);
            acc[1][2]=fmaf(alo.w,w1.z,acc[1][2]); acc[1][3]=fmaf(alo.w,w1.w,acc[1][3]);
            acc[2][0]=fmaf(ahi.y,w1.x,acc[2][0]); acc[2][1]=fmaf(ahi.y,w1.y,acc[2][1]);
            acc[2][2]=fmaf(ahi.y,w1.z,acc[2][2]); acc[2][3]=fmaf(ahi.y,w1.w,acc[2][3]);
            acc[3][0]=fmaf(ahi.w,w1.x,acc[3][0]); acc[3][1]=fmaf(ahi.w,w1.y,acc[3][1]);
            acc[3][2]=fmaf(ahi.w,w1.z,acc[3][2]); acc[3][3]=fmaf(ahi.w,w1.w,acc[3][3]);
        }
    };
    auto phase = [&](int NT, int split, const float* srcA, const float* srcB,
                     float (&acc)[4][4]) {
        if (wv < 4) { issueA(srcA, buf); WAITVM(0); }
        LGKM_BAR();
        for (int t = 0; t < NT; ++t) {
            if (wv < 4) {
                if (t + 1 < NT) {
                    const float* s = (t + 1 < split) ? srcA + (size_t)(t + 1) * 8192
                                                     : srcB + (size_t)(t + 1 - split) * 8192;
                    issueA(s, buf ^ 1);
                }
            } else {
                int s4 = (g5 + 4 >= 5) ? g5 - 1 : g5 + 4;   // (g+4)%5
                issueW(g + 4, s4);
            }
            computeTile(buf, g5, acc);
            if (wv < 4) {
                if (t + 1 < NT) WAITVM(0);
            } else {
                int rem = GTOT - 1 - g;
                if (rem >= 4)      { WAITVM(6); }
                else if (rem == 3) { WAITVM(4); }
                else if (rem == 2) { WAITVM(2); }
                else if (rem == 1) { WAITVM(0); }
            }
            LGKM_BAR();
            buf ^= 1;
            ++g;
            g5 = (g5 == 4) ? 0 : g5 + 1;
        }
    };
    auto finishCell = [&](float (&acc)[4][4], const float (&bq)[4], float& cr,
                          float* hdst) {
        #pragma unroll
        for (int i = 0; i < 4; ++i)
            Pred4[wv][lane][i] = make_float4(acc[i][0], acc[i][1], acc[i][2], acc[i][3]);
        LGKM_BAR();
        #pragma unroll
        for (int u = 0; u < 2; ++u) {
            int e = (tid << 1) + u;
            int p = e >> 4, ij = e & 15;
            int i = ij >> 2, j = ij & 3;
            float s = 0.f;
            #pragma unroll
            for (int w = 0; w < 8; ++w)
                s += ((const float*)&Pred4[w][p][i])[j];    // fixed order
            int rr = ((i >> 1) << 5) + ((p & 15) << 1) + (i & 1);
            int cl = ((p >> 4) << 2) + j;
            Sx[cl][rr] = s;
        }
        LGKM_BAR();
        if (tid < 256) {
            int gr = tid >> 2, gi = tid & 3;
            float fg = sigmoidf_(Sx[gi][gr]      + bq[0]);
            float ig = sigmoidf_(Sx[4 + gi][gr]  + bq[1]);
            float og = sigmoidf_(Sx[8 + gi][gr]  + bq[2]);
            float gg = tanhf(    Sx[12 + gi][gr] + bq[3]);
            cr = fg * cr + ig * gg;
            hdst[tidx(gr, colbase + gi)] = og * tanhf(cr);
        }
    };

    // seed W ring with tiles 0..3
    if (wv >= 4) {
        issueW(0, 0); issueW(1, 1); issueW(2, 2); issueW(3, 3);
        WAITVM(6);
    }

    for (int t = 0; t < T_STEPS; ++t) {
        const float* eT     = embT + (size_t)t * ESLOT;
        const float* h0prev = h0T + (size_t)((t + 1) & 1) * HSLOT;
        float*       h0cur  = h0T + (size_t)(t & 1) * HSLOT;
        const float* h1prev = (t == 0) ? h1iT : HST + (size_t)(t - 1) * HSLOT;
        float*       h1cur  = HST + (size_t)t * HSLOT;

        {
            float acc[4][4] = {};
            phase(12, 4, eT, h0prev, acc);
            finishCell(acc, bf0, c0r, h0cur);
        }
        grid_barrier(bar, t, bid, tid, wv);   // drains waves 0-3 (h0), keeps W ring
        {
            float acc[4][4] = {};
            phase(16, 8, h0cur, h1prev, acc);
            finishCell(acc, bf1, c1r, h1cur);
        }
        // h1(t) stores drained at grid_barrier(t+1) before any block reads them
    }
}

// ---------------------------------------------------------------------------
// Parallel GEMM: C[M,N] = A[M,K] @ B[K,N]. 128x64 tile, 8x4 micro.
// AMODE: 0 row-major f32, 1 transposed HST (tidx), 2 bf16 row-major.
// CMODE: 0 f32 (+bias,relu), 1 transposed embT scatter, 2 bf16 store.
// ---------------------------------------------------------------------------
template<int AMODE, int CMODE>
__global__ __launch_bounds__(256)
void gemm128(const float* __restrict__ A, const float* __restrict__ B,
             const float* __restrict__ bias, float* __restrict__ C,
             int M, int N, int K, int relu)
{
    __shared__ float As[16][132];
    __shared__ float Bs[16][64];

    const int tid = threadIdx.x;
    const int tx = tid & 15, ty = tid >> 4;
    const int m0 = blockIdx.y << 7, n0 = blockIdx.x << 6;
    float acc[8][4] = {};

    for (int kk = 0; kk < K; kk += 16) {
        if (AMODE == 0) {
            #pragma unroll
            for (int i = 0; i < 8; ++i) {
                int e = tid + (i << 8);
                int r = e >> 4, k = e & 15;
                As[k][r] = A[(size_t)(m0 + r) * K + kk + k];
            }
        } else if (AMODE == 1) {
            #pragma unroll
            for (int i = 0; i < 8; ++i) {
                int e = tid + (i << 8);
                int k = e >> 7, rr = e & 127;
                int gm = m0 + rr, tt = gm >> 6, b = gm & 63;
                As[k][rr] = A[(size_t)tt * HSLOT + tidx(b, kk + k)];
            }
        } else {
            #pragma unroll
            for (int i = 0; i < 8; ++i) {
                int e = tid + (i << 8);
                int r = e >> 4, k = e & 15;
                As[k][r] = __bfloat162float(
                    ((const __hip_bfloat16*)A)[(size_t)(m0 + r) * K + kk + k]);
            }
        }
        #pragma unroll
        for (int i = 0; i < 4; ++i) {
            int e = tid + (i << 8);
            int r = e >> 6, c = e & 63;
            Bs[r][c] = B[(size_t)(kk + r) * N + n0 + c];
        }
        __syncthreads();
        #pragma unroll
        for (int k = 0; k < 16; ++k) {
            float4 a0 = *(const float4*)&As[k][(ty << 3)];
            float4 a1 = *(const float4*)&As[k][(ty << 3) + 4];
            float4 b4 = *(const float4*)&Bs[k][(tx << 2)];
            float a[8] = {a0.x, a0.y, a0.z, a0.w, a1.x, a1.y, a1.z, a1.w};
            float b[4] = {b4.x, b4.y, b4.z, b4.w};
            #pragma unroll
            for (int i = 0; i < 8; ++i)
                #pragma unroll
                for (int j = 0; j < 4; ++j)
                    acc[i][j] = fmaf(a[i], b[j], acc[i][j]);
        }
        __syncthreads();
    }

    #pragma unroll
    for (int i = 0; i < 8; ++i) {
        int gm = m0 + (ty << 3) + i;
        if (CMODE == 0) {
            float4 o;
            float* op = (float*)&o;
            #pragma unroll
            for (int j = 0; j < 4; ++j) {
                int gn = n0 + (tx << 2) + j;
                float v = acc[i][j] + (bias ? bias[gn] : 0.0f);
                if (relu) v = fmaxf(v, 0.0f);
                op[j] = v;
            }
            *(float4*)&C[(size_t)gm * N + n0 + (tx << 2)] = o;
        } else if (CMODE == 1) {
            int tt = gm >> 6, b = gm & 63;
            int gn = n0 + (tx << 2);
            float* base = C + (size_t)tt * ESLOT;
            *(float2*)&base[tidx(b, gn)]     = make_float2(acc[i][0], acc[i][1]);
            *(float2*)&base[tidx(b, gn + 2)] = make_float2(acc[i][2], acc[i][3]);
        } else {
            #pragma unroll
            for (int j = 0; j < 4; ++j) {
                int gn = n0 + (tx << 2) + j;
                float v = acc[i][j] + (bias ? bias[gn] : 0.0f);
                if (relu) v = fmaxf(v, 0.0f);
                ((__hip_bfloat16*)C)[(size_t)gm * N + gn] = __float2bfloat16(v);
            }
        }
    }
}

// pack Wsrc[k][gate*HN + colbase(b) + j] -> Wp[b][k][gate*4+j]
__global__ __launch_bounds__(256)
void pack_w(const float* __restrict__ Wsrc, float* __restrict__ WpA,
            float* __restrict__ WpB, int K, int splitB)
{
    long idx = (long)blockIdx.x * 256 + threadIdx.x;
    int c = (int)(idx & 15);
    long r = idx >> 4;                 // b*K + k
    int b = (int)(r / K);
    int k = (int)(r - (long)b * K);
    int colbase = ((b & 7) << 7) + ((b >> 3) << 2);
    float v = Wsrc[(size_t)k * SDIM + (c >> 2) * HN + colbase + (c & 3)];
    if (b < splitB) WpA[((size_t)b * K + k) * 16 + c] = v;
    else            WpB[((size_t)(b - splitB) * K + k) * 16 + c] = v;
}

// zero barrier + transpose initial h states
__global__ __launch_bounds__(256)
void init_misc(const float* __restrict__ h0_in, const float* __restrict__ h1_in,
               float* __restrict__ h0T, float* __restrict__ h1iT, int* bar)
{
    int i = blockIdx.x * 256 + threadIdx.x;
    if (i < 1024) bar[i] = 0;
    if (i < BHN) {
        int b = i >> 10, col = i & 1023;
        h0T[HSLOT + tidx(b, col)] = h0_in[i];   // slot 1 = h0(-1)
        h1iT[tidx(b, col)] = h1_in[i];
    }
}

extern "C" void kernel_launch(void* const* d_in, const int* in_sizes, int n_in,
                              void* d_out, int out_size, void* d_ws, size_t ws_size,
                              hipStream_t stream) {
    const float* inputs     = (const float*)d_in[0];
    const float* h0_in      = (const float*)d_in[1];
    const float* c0_in      = (const float*)d_in[2];
    const float* h1_in      = (const float*)d_in[3];
    const float* c1_in      = (const float*)d_in[4];
    const float* emb_matrix = (const float*)d_in[5];
    const float* lstm_w0    = (const float*)d_in[6];
    const float* lstm_b0    = (const float*)d_in[7];
    const float* lstm_w1    = (const float*)d_in[8];
    const float* lstm_b1    = (const float*)d_in[9];
    const float* out_w0     = (const float*)d_in[10];
    const float* out_b0     = (const float*)d_in[11];
    const float* out_w1     = (const float*)d_in[12];
    const float* out_b1     = (const float*)d_in[13];
    float* logits = (float*)d_out;

    const int MB = T_STEPS * BATCH;  // 12800

    // workspace (floats), ~125 MB:
    float* ws   = (float*)d_ws;
    float* embT = ws;                                    //  6,553,600 (26.2 MB)
    float* Wp0  = embT + (size_t)T_STEPS * ESLOT;        //  6,291,456 (25.2 MB)
    float* Wp1a = Wp0  + (size_t)NBLK * 1536 * 16;       //  5,111,808 (20.4 MB)
    float* HST  = Wp1a + (size_t)W1SPLIT * 2048 * 16;    // 13,107,200 (52.4 MB)
    float* h0T  = HST  + (size_t)T_STEPS * HSLOT;        //    131,072
    float* h1iT = h0T  + 2 * (size_t)HSLOT;              //     65,536
    int*   bar  = (int*)(h1iT + (size_t)BHN);            //      1,024
    // hid (bf16, 26.21 MB) aliases embT exactly; embT dead post-recurrence.
    __hip_bfloat16* hid = (__hip_bfloat16*)embT;
    // Wp1b: 100 block-slices = 3,276,800 floats = d_out exactly; dead before
    // the final logits GEMM overwrites d_out.
    float* Wp1b = (float*)d_out;

    init_misc<<<dim3(256), 256, 0, stream>>>(h0_in, h1_in, h0T, h1iT, bar);
    pack_w<<<dim3(24576), 256, 0, stream>>>(lstm_w0, Wp0, Wp0, 1536, NBLK);
    pack_w<<<dim3(32768), 256, 0, stream>>>(lstm_w1, Wp1a, Wp1b, 2048, W1SPLIT);

    // embT = (inputs @ emb_matrix), transposed-interleaved
    gemm128<0, 1><<<dim3(EMB / 64, MB / 128), 256, 0, stream>>>(
        inputs, emb_matrix, nullptr, embT, MB, EMB, VOCAB, 0);

    lstm_persistent<<<dim3(NBLK), 512, 0, stream>>>(
        embT, c0_in, c1_in, Wp0, Wp1a, Wp1b, lstm_b0, lstm_b1,
        h0T, HST, h1iT, bar);

    // hid(bf16) = relu(HS @ out_w0 + out_b0), A from transposed HST
    gemm128<1, 2><<<dim3(ON_ / 64, MB / 128), 256, 0, stream>>>(
        HST, out_w0, out_b0, (float*)hid, MB, ON_, HN, 1);

    // logits = hid @ out_w1 + out_b1 (overwrites Wp1b region of d_out)
    gemm128<2, 0><<<dim3(VOCAB / 64, MB / 128), 256, 0, stream>>>(
        (const float*)hid, out_w1, out_b1, logits, MB, VOCAB, ON_, 0);
}

// Round 11
// 12980.971 us; speedup vs baseline: 4.8229x; 1.0066x over previous
//
#include <hip/hip_runtime.h>
#include <hip/hip_bf16.h>
#include <math.h>

#define T_STEPS 200
#define BATCH   64
#define VOCAB   256
#define EMB     512
#define HN      1024
#define ON_     1024
#define SDIM    4096
#define NBLK    256
#define BHN     65536          // floats per h vector (64 x 1024)
#define HSLOT   65536
#define ESLOT   32768          // floats per emb step (64 x 512)
#define NGRP    8
#define GSZ     32
#define GTOT    (T_STEPS * 28) // 12 L0-tiles + 16 L1-tiles per step
#define W1SPLIT 156

typedef __attribute__((address_space(1))) const void gas_t;
typedef __attribute__((address_space(3))) void las_t;
#define GLDS(gp, lp) __builtin_amdgcn_global_load_lds((gas_t*)(gp), (las_t*)(lp), 16, 0, 0)
#define WAITVM(n) asm volatile("s_waitcnt vmcnt(" #n ")" ::: "memory")
#define LGKM0()   asm volatile("s_waitcnt lgkmcnt(0)" ::: "memory")
#define LGKM_BAR() do { LGKM0(); \
    __builtin_amdgcn_s_barrier(); asm volatile("" ::: "memory"); } while (0)

__device__ __forceinline__ float sigmoidf_(float x) {
    return 1.0f / (1.0f + __expf(-x));
}

// transposed activation layout: pair-block of 512B, rows {2q,2q+1} then {2q+32,2q+33}
__device__ __forceinline__ int tidx(int b, int k) {
    return ((k >> 1) << 7) + ((b >> 5) << 6) + (((b & 31) >> 1) << 2) + ((b & 1) << 1) + (k & 1);
}

// ---------------------------------------------------------------------------
// Grid barrier: waves 0-3 drain their stores (h writes), raw s_barrier keeps
// waves 4-7's W-ring loads in flight. tid0 fence+atomics = R5/R7-proven.
// ---------------------------------------------------------------------------
__device__ __forceinline__ void grid_barrier(int* bar, int step, int bid, int tid, int wv) {
    if (wv < 4) { WAITVM(0); }
    LGKM0();
    __builtin_amdgcn_s_barrier();
    if (tid == 0) {
        __threadfence();
        const int gidx = bid & (NGRP - 1);
        int* lcnt = bar + gidx * 32;
        int* lgen = bar + (NGRP + gidx) * 32;
        int* gcnt = bar + (2 * NGRP) * 32;
        int* ggen = bar + (2 * NGRP + 1) * 32;
        int a = __hip_atomic_fetch_add(lcnt, 1, __ATOMIC_ACQ_REL, __HIP_MEMORY_SCOPE_AGENT);
        if (a == GSZ * (step + 1) - 1) {
            int b = __hip_atomic_fetch_add(gcnt, 1, __ATOMIC_ACQ_REL, __HIP_MEMORY_SCOPE_AGENT);
            if (b == NGRP * (step + 1) - 1) {
                __hip_atomic_store(ggen, step + 1, __ATOMIC_RELEASE, __HIP_MEMORY_SCOPE_AGENT);
            } else {
                while (__hip_atomic_load(ggen, __ATOMIC_ACQUIRE, __HIP_MEMORY_SCOPE_AGENT) <= step)
                    __builtin_amdgcn_s_sleep(2);
            }
            __hip_atomic_store(lgen, step + 1, __ATOMIC_RELEASE, __HIP_MEMORY_SCOPE_AGENT);
        } else {
            while (__hip_atomic_load(lgen, __ATOMIC_ACQUIRE, __HIP_MEMORY_SCOPE_AGENT) <= step)
                __builtin_amdgcn_s_sleep(2);
        }
        __threadfence();
    }
    asm volatile("" ::: "memory");
    __builtin_amdgcn_s_barrier();
    asm volatile("" ::: "memory");
}

// ---------------------------------------------------------------------------
// Persistent 2-layer LSTM. 256 blocks x 512 thr, block owns 4 h-cols
// (XCD-contiguous). Every wave stages EXACTLY the k-slice it computes:
// zero inter-wave syncs during tiles. Per wave per tile: 1 W-GLDS (1KB,
// private 4-slot ring, lookahead 3) + 4 A-GLDS (4KB, private 3-slot rot,
// lookahead 2), one in-order vmcnt stream with derived counts.
// ---------------------------------------------------------------------------
__global__ __launch_bounds__(512, 2)
void lstm_persistent(const float* __restrict__ embT,
                     const float* __restrict__ c0_in, const float* __restrict__ c1_in,
                     const float* __restrict__ Wp0,
                     const float* __restrict__ Wp1a, const float* __restrict__ Wp1b,
                     const float* __restrict__ b0v, const float* __restrict__ b1v,
                     float* __restrict__ h0T, float* __restrict__ HST,
                     const float* __restrict__ h1iT, int* bar)
{
    __shared__ float  Ab[8][3][1024];     // 96 KB: per-wave A slots (4KB each)
    __shared__ float  Wr[8][4][256];      // 32 KB: per-wave W ring (1KB each)
    __shared__ float4 Pred[4][64][5];     // 20 KB: 2-stage partials (pad 5)
    __shared__ float  Sx[16][66];         //  4 KB

    const int tid  = threadIdx.x;
    const int wv   = tid >> 6;
    const int lane = tid & 63;
    const int q    = lane & 15;
    const int c0   = (lane >> 4) << 2;
    const int bid  = blockIdx.x;
    const int colbase = ((bid & 7) << 7) + ((bid >> 3) << 2);

    const float* wp0 = Wp0 + (size_t)bid * ((EMB + HN) * 16) + (wv << 8);
    const float* wp1 = ((bid < W1SPLIT) ? Wp1a + (size_t)bid * (2 * HN * 16)
                                        : Wp1b + (size_t)(bid - W1SPLIT) * (2 * HN * 16))
                       + (wv << 8);

    float bf0[4], bf1[4], c0r = 0.f, c1r = 0.f;
    if (tid < 256) {
        int gr = tid >> 2, gi = tid & 3;
        c0r = c0_in[gr * HN + colbase + gi];
        c1r = c1_in[gr * HN + colbase + gi];
        #pragma unroll
        for (int gk = 0; gk < 4; ++gk) {
            bf0[gk] = b0v[gk * HN + colbase + gi];
            bf1[gk] = b1v[gk * HN + colbase + gi];
        }
    }

    int g = 0;   // global W-tile counter (28 per step)

    auto issueW = [&](int gt) {            // stage W tile gt into slot gt&3
        if (gt >= GTOT) return;
        int g28 = gt % 28;
        const float* s = (g28 < 12) ? wp0 + (size_t)g28 * 2048
                                    : wp1 + (size_t)(g28 - 12) * 2048;
        GLDS(s + (lane << 2), &Wr[wv][gt & 3][0]);
    };
    auto issueA = [&](const float* src, int slot) {   // wave's 4KB k-slice
        const float* p = src + (wv << 10) + (lane << 2);
        #pragma unroll
        for (int i = 0; i < 4; ++i)
            GLDS(p + (i << 8), &Ab[wv][slot][i << 8]);
    };
    auto computeTile = [&](int sa, int sw, float (&acc)[4][4]) {
        const float* abase = &Ab[wv][sa][q << 2];
        const float* wbase = &Wr[wv][sw][c0];
        #pragma unroll
        for (int pp = 0; pp < 8; ++pp) {
            float4 alo = *(const float4*)(abase + (pp << 7));
            float4 ahi = *(const float4*)(abase + (pp << 7) + 64);
            float4 w0  = *(const float4*)(wbase + (pp << 5));
            float4 w1  = *(const float4*)(wbase + (pp << 5) + 16);
            acc[0][0]=fmaf(alo.x,w0.x,acc[0][0]); acc[0][1]=fmaf(alo.x,w0.y,acc[0][1]);
            acc[0][2]=fmaf(alo.x,w0.z,acc[0][2]); acc[0][3]=fmaf(alo.x,w0.w,acc[0][3]);
            acc[1][0]=fmaf(alo.z,w0.x,acc[1][0]); acc[1][1]=fmaf(alo.z,w0.y,acc[1][1]);
            acc[1][2]=fmaf(alo.z,w0.z,acc[1][2]); acc[1][3]=fmaf(alo.z,w0.w,acc[1][3]);
            acc[2][0]=fmaf(ahi.x,w0.x,acc[2][0]); acc[2][1]=fmaf(ahi.x,w0.y,acc[2][1]);
            acc[2][2]=fmaf(ahi.x,w0.z,acc[2][2]); acc[2][3]=fmaf(ahi.x,w0.w,acc[2][3]);
            acc[3][0]=fmaf(ahi.z,w0.x,acc[3][0]); acc[3][1]=fmaf(ahi.z,w0.y,acc[3][1]);
            acc[3][2]=fmaf(ahi.z,w0.z,acc[3][2]); acc[3][3]=fmaf(ahi.z,w0.w,acc[3][3]);
            acc[0][0]=fmaf(alo.y,w1.x,acc[0][0]); acc[0][1]=fmaf(alo.y,w1.y,acc[0][1]);
            acc[0][2]=fmaf(alo.y,w1.z,acc[0][2]); acc[0][3]=fmaf(alo.y,w1.w,acc[0][3]);
            acc[1][0]=fmaf(alo.w,w1.x,acc[1][0]); acc[1][1]=fmaf(alo.w,w1.y,acc[1][1]);
            acc[1][2]=fmaf(alo.w,w1.z,acc[1][2]); acc[1][3]=fmaf(alo.w,w1.w,acc[1][3]);
            acc[2][0]=fmaf(ahi.y,w1.x,acc[2][0]); acc[2][1]=fmaf(ahi.y,w1.y,acc[2][1]);
            acc[2][2]=fmaf(ahi.y,w1.z,acc[2][2]); acc[2][3]=fmaf(ahi.y,w1.w,acc[2][3]);
            acc[3][0]=fmaf(ahi.w,w1.x,acc[3][0]); acc[3][1]=fmaf(ahi.w,w1.y,acc[3][1]);
            acc[3][2]=fmaf(ahi.w,w1.z,acc[3][2]); acc[3][3]=fmaf(ahi.w,w1.w,acc[3][3]);
        }
    };
    // One cell: NT tiles, A source lo for j<split else hi. No barriers inside.
    auto phase = [&](int NT, int split, const float* lo, const float* hi,
                     float (&acc)[4][4]) {
        auto srcA = [&](int j) -> const float* {
            return (j < split) ? lo + (size_t)j * 8192 : hi + (size_t)(j - split) * 8192;
        };
        LGKM0();                       // prior ds_reads retired before overwrite
        issueA(srcA(0), 0);
        issueA(srcA(1), 1);
        for (int j = 0; j < NT; ++j) {
            LGKM0();
            issueW(g + 3);
            if (j + 2 < NT) issueA(srcA(j + 2), (j + 2) % 3);
            // derived in-order vmcnt counts (see journal): steady queue =
            // [W(j+1), A(j)x4, W(j+2), A(j+1)x4, W(j+3), A(j+2)x4]
            if (j == 0)           { WAITVM(9); }
            else if (j < NT - 2)  { WAITVM(10); }
            else if (j == NT - 2) { WAITVM(6); }
            else                  { WAITVM(2); }
            computeTile(j % 3, g & 3, acc);
            ++g;
        }
    };
    auto finishCell = [&](float (&acc)[4][4], const float (&bq)[4], float& cr,
                          float* hdst) {
        if (wv >= 4) {
            #pragma unroll
            for (int i = 0; i < 4; ++i)
                Pred[wv - 4][lane][i] = make_float4(acc[i][0], acc[i][1], acc[i][2], acc[i][3]);
        }
        LGKM_BAR();
        if (wv < 4) {
            #pragma unroll
            for (int i = 0; i < 4; ++i) {
                float4 p = Pred[wv][lane][i];
                p.x += acc[i][0]; p.y += acc[i][1]; p.z += acc[i][2]; p.w += acc[i][3];
                Pred[wv][lane][i] = p;
            }
        }
        LGKM_BAR();
        #pragma unroll
        for (int u = 0; u < 2; ++u) {
            int e = (tid << 1) + u;
            int p = e >> 4, ij = e & 15;
            int i = ij >> 2, j = ij & 3;
            float s = 0.f;
            #pragma unroll
            for (int w = 0; w < 4; ++w)
                s += ((const float*)&Pred[w][p][i])[j];    // fixed order
            int rr = ((i >> 1) << 5) + ((p & 15) << 1) + (i & 1);
            int cl = ((p >> 4) << 2) + j;
            Sx[cl][rr] = s;
        }
        LGKM_BAR();
        if (tid < 256) {
            int gr = tid >> 2, gi = tid & 3;
            float fg = sigmoidf_(Sx[gi][gr]      + bq[0]);
            float ig = sigmoidf_(Sx[4 + gi][gr]  + bq[1]);
            float og = sigmoidf_(Sx[8 + gi][gr]  + bq[2]);
            float gg = tanhf(    Sx[12 + gi][gr] + bq[3]);
            cr = fg * cr + ig * gg;
            hdst[tidx(gr, colbase + gi)] = og * tanhf(cr);
        }
    };

    // seed W stream: tiles 0,1,2 -> slots 0,1,2 (lookahead established)
    issueW(0); issueW(1); issueW(2);

    for (int t = 0; t < T_STEPS; ++t) {
        const float* eT     = embT + (size_t)t * ESLOT;
        const float* h0prev = h0T + (size_t)((t + 1) & 1) * HSLOT;
        float*       h0cur  = h0T + (size_t)(t & 1) * HSLOT;
        const float* h1prev = (t == 0) ? h1iT : HST + (size_t)(t - 1) * HSLOT;
        float*       h1cur  = HST + (size_t)t * HSLOT;

        {
            float acc[4][4] = {};
            phase(12, 4, eT, h0prev, acc);
            finishCell(acc, bf0, c0r, h0cur);
        }
        grid_barrier(bar, t, bid, tid, wv);   // h0(t) visible; W ring survives
        {
            float acc[4][4] = {};
            phase(16, 8, h0cur, h1prev, acc);
            finishCell(acc, bf1, c1r, h1cur);
        }
        // h1(t) stores drained at grid_barrier(t+1) before any block reads them
    }
}

// ---------------------------------------------------------------------------
// Parallel GEMM: C[M,N] = A[M,K] @ B[K,N]. 128x64 tile, 8x4 micro.
// AMODE: 0 row-major f32, 1 transposed HST (tidx), 2 bf16 row-major.
// CMODE: 0 f32 (+bias,relu), 1 transposed embT scatter, 2 bf16 store.
// ---------------------------------------------------------------------------
template<int AMODE, int CMODE>
__global__ __launch_bounds__(256)
void gemm128(const float* __restrict__ A, const float* __restrict__ B,
             const float* __restrict__ bias, float* __restrict__ C,
             int M, int N, int K, int relu)
{
    __shared__ float As[16][132];
    __shared__ float Bs[16][64];

    const int tid = threadIdx.x;
    const int tx = tid & 15, ty = tid >> 4;
    const int m0 = blockIdx.y << 7, n0 = blockIdx.x << 6;
    float acc[8][4] = {};

    for (int kk = 0; kk < K; kk += 16) {
        if (AMODE == 0) {
            #pragma unroll
            for (int i = 0; i < 8; ++i) {
                int e = tid + (i << 8);
                int r = e >> 4, k = e & 15;
                As[k][r] = A[(size_t)(m0 + r) * K + kk + k];
            }
        } else if (AMODE == 1) {
            #pragma unroll
            for (int i = 0; i < 8; ++i) {
                int e = tid + (i << 8);
                int k = e >> 7, rr = e & 127;
                int gm = m0 + rr, tt = gm >> 6, b = gm & 63;
                As[k][rr] = A[(size_t)tt * HSLOT + tidx(b, kk + k)];
            }
        } else {
            #pragma unroll
            for (int i = 0; i < 8; ++i) {
                int e = tid + (i << 8);
                int r = e >> 4, k = e & 15;
                As[k][r] = __bfloat162float(
                    ((const __hip_bfloat16*)A)[(size_t)(m0 + r) * K + kk + k]);
            }
        }
        #pragma unroll
        for (int i = 0; i < 4; ++i) {
            int e = tid + (i << 8);
            int r = e >> 6, c = e & 63;
            Bs[r][c] = B[(size_t)(kk + r) * N + n0 + c];
        }
        __syncthreads();
        #pragma unroll
        for (int k = 0; k < 16; ++k) {
            float4 a0 = *(const float4*)&As[k][(ty << 3)];
            float4 a1 = *(const float4*)&As[k][(ty << 3) + 4];
            float4 b4 = *(const float4*)&Bs[k][(tx << 2)];
            float a[8] = {a0.x, a0.y, a0.z, a0.w, a1.x, a1.y, a1.z, a1.w};
            float b[4] = {b4.x, b4.y, b4.z, b4.w};
            #pragma unroll
            for (int i = 0; i < 8; ++i)
                #pragma unroll
                for (int j = 0; j < 4; ++j)
                    acc[i][j] = fmaf(a[i], b[j], acc[i][j]);
        }
        __syncthreads();
    }

    #pragma unroll
    for (int i = 0; i < 8; ++i) {
        int gm = m0 + (ty << 3) + i;
        if (CMODE == 0) {
            float4 o;
            float* op = (float*)&o;
            #pragma unroll
            for (int j = 0; j < 4; ++j) {
                int gn = n0 + (tx << 2) + j;
                float v = acc[i][j] + (bias ? bias[gn] : 0.0f);
                if (relu) v = fmaxf(v, 0.0f);
                op[j] = v;
            }
            *(float4*)&C[(size_t)gm * N + n0 + (tx << 2)] = o;
        } else if (CMODE == 1) {
            int tt = gm >> 6, b = gm & 63;
            int gn = n0 + (tx << 2);
            float* base = C + (size_t)tt * ESLOT;
            *(float2*)&base[tidx(b, gn)]     = make_float2(acc[i][0], acc[i][1]);
            *(float2*)&base[tidx(b, gn + 2)] = make_float2(acc[i][2], acc[i][3]);
        } else {
            #pragma unroll
            for (int j = 0; j < 4; ++j) {
                int gn = n0 + (tx << 2) + j;
                float v = acc[i][j] + (bias ? bias[gn] : 0.0f);
                if (relu) v = fmaxf(v, 0.0f);
                ((__hip_bfloat16*)C)[(size_t)gm * N + gn] = __float2bfloat16(v);
            }
        }
    }
}

// pack Wsrc[k][gate*HN + colbase(b) + j] -> Wp[b][k][gate*4+j]
__global__ __launch_bounds__(256)
void pack_w(const float* __restrict__ Wsrc, float* __restrict__ WpA,
            float* __restrict__ WpB, int K, int splitB)
{
    long idx = (long)blockIdx.x * 256 + threadIdx.x;
    int c = (int)(idx & 15);
    long r = idx >> 4;                 // b*K + k
    int b = (int)(r / K);
    int k = (int)(r - (long)b * K);
    int colbase = ((b & 7) << 7) + ((b >> 3) << 2);
    float v = Wsrc[(size_t)k * SDIM + (c >> 2) * HN + colbase + (c & 3)];
    if (b < splitB) WpA[((size_t)b * K + k) * 16 + c] = v;
    else            WpB[((size_t)(b - splitB) * K + k) * 16 + c] = v;
}

// zero barrier + transpose initial h states
__global__ __launch_bounds__(256)
void init_misc(const float* __restrict__ h0_in, const float* __restrict__ h1_in,
               float* __restrict__ h0T, float* __restrict__ h1iT, int* bar)
{
    int i = blockIdx.x * 256 + threadIdx.x;
    if (i < 1024) bar[i] = 0;
    if (i < BHN) {
        int b = i >> 10, col = i & 1023;
        h0T[HSLOT + tidx(b, col)] = h0_in[i];   // slot 1 = h0(-1)
        h1iT[tidx(b, col)] = h1_in[i];
    }
}

extern "C" void kernel_launch(void* const* d_in, const int* in_sizes, int n_in,
                              void* d_out, int out_size, void* d_ws, size_t ws_size,
                              hipStream_t stream) {
    const float* inputs     = (const float*)d_in[0];
    const float* h0_in      = (const float*)d_in[1];
    const float* c0_in      = (const float*)d_in[2];
    const float* h1_in      = (const float*)d_in[3];
    const float* c1_in      = (const float*)d_in[4];
    const float* emb_matrix = (const float*)d_in[5];
    const float* lstm_w0    = (const float*)d_in[6];
    const float* lstm_b0    = (const float*)d_in[7];
    const float* lstm_w1    = (const float*)d_in[8];
    const float* lstm_b1    = (const float*)d_in[9];
    const float* out_w0     = (const float*)d_in[10];
    const float* out_b0     = (const float*)d_in[11];
    const float* out_w1     = (const float*)d_in[12];
    const float* out_b1     = (const float*)d_in[13];
    float* logits = (float*)d_out;

    const int MB = T_STEPS * BATCH;  // 12800

    // workspace (floats), ~125 MB:
    float* ws   = (float*)d_ws;
    float* embT = ws;                                    //  6,553,600 (26.2 MB)
    float* Wp0  = embT + (size_t)T_STEPS * ESLOT;        //  6,291,456 (25.2 MB)
    float* Wp1a = Wp0  + (size_t)NBLK * 1536 * 16;       //  5,111,808 (20.4 MB)
    float* HST  = Wp1a + (size_t)W1SPLIT * 2048 * 16;    // 13,107,200 (52.4 MB)
    float* h0T  = HST  + (size_t)T_STEPS * HSLOT;        //    131,072
    float* h1iT = h0T  + 2 * (size_t)HSLOT;              //     65,536
    int*   bar  = (int*)(h1iT + (size_t)BHN);            //      1,024
    // hid (bf16, 26.21 MB) aliases embT exactly; embT dead post-recurrence.
    __hip_bfloat16* hid = (__hip_bfloat16*)embT;
    // Wp1b: 100 block-slices = 3,276,800 floats = d_out exactly; dead before
    // the final logits GEMM overwrites d_out.
    float* Wp1b = (float*)d_out;

    init_misc<<<dim3(256), 256, 0, stream>>>(h0_in, h1_in, h0T, h1iT, bar);
    pack_w<<<dim3(24576), 256, 0, stream>>>(lstm_w0, Wp0, Wp0, 1536, NBLK);
    pack_w<<<dim3(32768), 256, 0, stream>>>(lstm_w1, Wp1a, Wp1b, 2048, W1SPLIT);

    // embT = (inputs @ emb_matrix), transposed-interleaved
    gemm128<0, 1><<<dim3(EMB / 64, MB / 128), 256, 0, stream>>>(
        inputs, emb_matrix, nullptr, embT, MB, EMB, VOCAB, 0);

    lstm_persistent<<<dim3(NBLK), 512, 0, stream>>>(
        embT, c0_in, c1_in, Wp0, Wp1a, Wp1b, lstm_b0, lstm_b1,
        h0T, HST, h1iT, bar);

    // hid(bf16) = relu(HS @ out_w0 + out_b0), A from transposed HST
    gemm128<1, 2><<<dim3(ON_ / 64, MB / 128), 256, 0, stream>>>(
        HST, out_w0, out_b0, (float*)hid, MB, ON_, HN, 1);

    // logits = hid @ out_w1 + out_b1 (overwrites Wp1b region of d_out)
    gemm128<2, 0><<<dim3(VOCAB / 64, MB / 128), 256, 0, stream>>>(
        (const float*)hid, out_w1, out_b1, logits, MB, VOCAB, ON_, 0);
}